// Round 10
// baseline (77.364 us; speedup 1.0000x reference)
//
#include <hip/hip_runtime.h>

typedef __attribute__((ext_vector_type(4))) float f32x4;
typedef __attribute__((ext_vector_type(8))) short bf16x8;

// f32 -> bf16 round-to-nearest-even
__device__ inline unsigned short f2bf(float x) {
  unsigned u = __builtin_bit_cast(unsigned, x);
  u += 0x7fffu + ((u >> 16) & 1u);
  return (unsigned short)(u >> 16);
}

__device__ inline bf16x8 pack8(f32x4 lo, f32x4 hi) {
  bf16x8 r;
  r[0] = (short)f2bf(lo[0]); r[1] = (short)f2bf(lo[1]);
  r[2] = (short)f2bf(lo[2]); r[3] = (short)f2bf(lo[3]);
  r[4] = (short)f2bf(hi[0]); r[5] = (short)f2bf(hi[1]);
  r[6] = (short)f2bf(hi[2]); r[7] = (short)f2bf(hi[3]);
  return r;
}

__device__ inline bf16x8 cvt8(const float* __restrict__ p) {
  return pack8(*(const f32x4*)p, *(const f32x4*)(p + 4));
}

// prep: Wu[512][768] = [W1r;W1c] @ Wr (f32 accum, bf16 out),
//       buv[512] = [W1r;W1c] @ br (+ b1 on u-half); zero cvec.
// 128 blocks x 256 thr; block owns 4 output rows.
__global__ __launch_bounds__(256) void prep_kernel(
    const float* __restrict__ Wr, const float* __restrict__ br,
    const float* __restrict__ W1, const float* __restrict__ b1,
    unsigned short* __restrict__ Wubf, float* __restrict__ buv,
    float* __restrict__ cvec) {
  __shared__ float w1s[4][128];
  int tid = threadIdx.x;
  int r0 = blockIdx.x * 4;
  // 512 entries, 256 threads -> 2 per thread
  for (int i = tid; i < 512; i += 256) {
    int rr = i >> 7, kk = i & 127;
    int r = r0 + rr;
    int m = r & 255, half = (r >> 8) & 1;
    w1s[rr][kk] = W1[(size_t)m * 256 + half * 128 + kk];
  }
  if (tid < 32) cvec[blockIdx.x * 32 + tid] = 0.f;  // 128*32 = 4096 floats
  __syncthreads();
  float acc[3][4] = {{0.f,0.f,0.f,0.f},{0.f,0.f,0.f,0.f},{0.f,0.f,0.f,0.f}};
#pragma unroll 4
  for (int k = 0; k < 128; ++k) {
    float w0 = w1s[0][k], w1v = w1s[1][k], w2v = w1s[2][k], w3v = w1s[3][k];
#pragma unroll
    for (int p = 0; p < 3; ++p) {
      float wr = Wr[(size_t)k * 768 + p * 256 + tid];
      acc[p][0] = fmaf(w0, wr, acc[p][0]);
      acc[p][1] = fmaf(w1v, wr, acc[p][1]);
      acc[p][2] = fmaf(w2v, wr, acc[p][2]);
      acc[p][3] = fmaf(w3v, wr, acc[p][3]);
    }
  }
#pragma unroll
  for (int p = 0; p < 3; ++p)
#pragma unroll
    for (int rr = 0; rr < 4; ++rr)
      Wubf[(size_t)(r0 + rr) * 768 + p * 256 + tid] = f2bf(acc[p][rr]);
  if (tid < 4) {
    int r = r0 + tid;
    float s = 0.f;
    for (int k = 0; k < 128; ++k) s = fmaf(w1s[tid][k], br[k], s);
    buv[r] = s + (r < 256 ? b1[r] : 0.f);
  }
}

// biggemm: UVt[512][2048] f32 = Wu @ X^T + buv; fused cvec epilogue
// (shfl-reduce + atomicAdd, exactly the round-5-passed gemm2 pattern).
// Wave: 16m x 32t. Grid (64,8) = 512 blocks.
__global__ __launch_bounds__(256) void biggemm_kernel(
    const float* __restrict__ X, const unsigned short* __restrict__ Wubf,
    const float* __restrict__ buv, const float* __restrict__ W2,
    float* __restrict__ UVt, float* __restrict__ cvec) {
  int wave = threadIdx.x >> 6, lane = threadIdx.x & 63;
  int t0 = blockIdx.x * 32;
  int m0 = blockIdx.y * 64 + wave * 16;
  int lr = lane & 15, kg = (lane >> 4) * 8;
  const unsigned short* aB = Wubf + (size_t)(m0 + lr) * 768 + kg;
  const float* bp0 = X + (size_t)(t0 + lr) * 768 + kg;
  const float* bp1 = X + (size_t)(t0 + 16 + lr) * 768 + kg;
  f32x4 acc0 = {0,0,0,0}, acc1 = {0,0,0,0};
#pragma unroll 4
  for (int k0 = 0; k0 < 768; k0 += 32) {
    bf16x8 a = *(const bf16x8*)(aB + k0);
    bf16x8 b0 = cvt8(bp0 + k0);
    bf16x8 b1f = cvt8(bp1 + k0);
    acc0 = __builtin_amdgcn_mfma_f32_16x16x32_bf16(a, b0, acc0, 0, 0, 0);
    acc1 = __builtin_amdgcn_mfma_f32_16x16x32_bf16(a, b1f, acc1, 0, 0, 0);
  }
  int rb = (lane >> 4) * 4;
  float p0 = 0.f, p1 = 0.f;
#pragma unroll
  for (int r = 0; r < 4; ++r) {
    int m = m0 + rb + r;
    float bias = buv[m];
    float w2v = W2[m & 255];
    float v0 = acc0[r] + bias;
    float v1 = acc1[r] + bias;
    UVt[(size_t)m * 2048 + t0 + lr] = v0;
    UVt[(size_t)m * 2048 + t0 + 16 + lr] = v1;
    p0 = fmaf(w2v, v0, p0);
    p1 = fmaf(w2v, v1, p1);
  }
  p0 += __shfl_xor(p0, 16); p0 += __shfl_xor(p0, 32);
  p1 += __shfl_xor(p1, 16); p1 += __shfl_xor(p1, 32);
  if (lane < 16) {
    int h = (m0 < 256) ? 0 : 1;
    atomicAdd(&cvec[h * 2048 + t0 + lane], 0.5f * p0);
    atomicAdd(&cvec[h * 2048 + t0 + 16 + lane], 0.5f * p1);
  }
}

// Pairwise (round-5 passed version, verbatim): 32x32 tile/block, 4 waves
// m-split, [m][tok] LDS, 4x4/lane abs-trick outer product; all-wave combine
// + mirrored writes via LDS.
__global__ __launch_bounds__(256, 2) void pairwise_kernel(
    const float* __restrict__ UVt, const float* __restrict__ W2,
    const float* __restrict__ cvec, const float* __restrict__ b2p,
    float* __restrict__ Out) {
  __shared__ float u_s[4][64][36];
  __shared__ float v_s[4][64][36];
  __shared__ float w2_s[256];
  __shared__ float cuv[64];

  int tid = threadIdx.x;
  int wave = tid >> 6, lane = tid & 63;
  int b = blockIdx.y;
  int p = blockIdx.x;
  int it = 0;
  while (p >= 32 - it) { p -= 32 - it; ++it; }
  int jt = it + p;

  int utok = b * 1024 + it * 32;
  int vtok = b * 1024 + jt * 32;

  w2_s[tid] = W2[tid];
  if (tid < 32) cuv[tid] = cvec[utok + tid];
  else if (tid < 64) cuv[tid] = cvec[2048 + vtok + (tid - 32)];
  __syncthreads();  // w2_s/cuv visible; main loop LDS is wave-private

  int mr = lane >> 3, tq = (lane & 7) * 4;
  int tx = lane & 7, ty = lane >> 3;
  float acc[4][4] = {{0,0,0,0},{0,0,0,0},{0,0,0,0},{0,0,0,0}};

  // stage this wave's 64-m slice
#pragma unroll
  for (int g = 0; g < 8; ++g) {
    int ml = g * 8 + mr;
    int m = wave * 64 + ml;
    *(f32x4*)&u_s[wave][ml][tq] = *(const f32x4*)(UVt + (size_t)m * 2048 + utok + tq);
    *(f32x4*)&v_s[wave][ml][tq] = *(const f32x4*)(UVt + (size_t)(256 + m) * 2048 + vtok + tq);
  }

  for (int ml = 0; ml < 64; ml += 4) {
    f32x4 wq = *(const f32x4*)&w2_s[wave * 64 + ml];
#pragma unroll
    for (int s = 0; s < 4; ++s) {
      f32x4 uu = *(const f32x4*)&u_s[wave][ml + s][4 * ty];
      f32x4 vv = *(const f32x4*)&v_s[wave][ml + s][4 * tx];
      float w = wq[s];
#pragma unroll
      for (int i = 0; i < 4; ++i)
#pragma unroll
        for (int j = 0; j < 4; ++j)
          acc[i][j] = fmaf(w, fabsf(uu[i] + vv[j]), acc[i][j]);
    }
  }

  // all-wave combine via LDS overlays
  float* ovp = (float*)u_s;   // [4][32][36] partials
  float* t2p = (float*)v_s;   // [32][36] transposed tile
  __syncthreads();            // all main-loop reads done before overlay writes
#pragma unroll
  for (int i = 0; i < 4; ++i) {
    f32x4 rv = {acc[i][0], acc[i][1], acc[i][2], acc[i][3]};
    *(f32x4*)&ovp[((size_t)wave * 32 + 4 * ty + i) * 36 + 4 * tx] = rv;
  }
  __syncthreads();

  int ly = lane >> 3, tc = lane & 7;   // row-within-wave, col group
  int row = wave * 8 + ly;
  float b2v = b2p[0];
  f32x4 sum = {0, 0, 0, 0};
#pragma unroll
  for (int q = 0; q < 4; ++q) {
    f32x4 part = *(const f32x4*)&ovp[((size_t)q * 32 + row) * 36 + 4 * tc];
#pragma unroll
    for (int j = 0; j < 4; ++j) sum[j] += part[j];
  }
  float cu = cuv[row];
  f32x4 val;
#pragma unroll
  for (int j = 0; j < 4; ++j)
    val[j] = 0.5f * sum[j] + cu + cuv[32 + 4 * tc + j] + b2v;

  // write transposed copy for mirror
  *(f32x4*)&t2p[(size_t)row * 36 + 4 * tc] = val;

  size_t obase = (size_t)b << 20;
  int i0 = it * 32, j0 = jt * 32;
  if (it != jt)
    *(f32x4*)(Out + obase + (size_t)(i0 + row) * 1024 + j0 + 4 * tc) = val;
  else {
#pragma unroll
    for (int j = 0; j < 4; ++j) {
      int jl = 4 * tc + j;
      if (jl >= row) Out[obase + (size_t)(i0 + row) * 1024 + j0 + jl] = val[j];
    }
  }
  __syncthreads();  // t2p complete
  f32x4 mv;
#pragma unroll
  for (int j = 0; j < 4; ++j) mv[j] = t2p[(size_t)(4 * tc + j) * 36 + row];
  if (it != jt)
    *(f32x4*)(Out + obase + (size_t)(j0 + row) * 1024 + i0 + 4 * tc) = mv;
  else {
#pragma unroll
    for (int j = 0; j < 4; ++j) {
      int c = 4 * tc + j;
      if (row > c) Out[obase + (size_t)(i0 + row) * 1024 + j0 + c] = mv[j];
    }
  }
}

extern "C" void kernel_launch(void* const* d_in, const int* in_sizes, int n_in,
                              void* d_out, int out_size, void* d_ws, size_t ws_size,
                              hipStream_t stream) {
  (void)in_sizes; (void)n_in; (void)out_size; (void)ws_size;
  const float* X  = (const float*)d_in[0];
  const float* Wr = (const float*)d_in[1];
  const float* br = (const float*)d_in[2];
  const float* W1 = (const float*)d_in[3];
  const float* b1 = (const float*)d_in[4];
  const float* W2 = (const float*)d_in[5];
  const float* b2 = (const float*)d_in[6];
  float* Out = (float*)d_out;

  char* ws = (char*)d_ws;
  unsigned short* Wubf = (unsigned short*)(ws);            //   786,432 B
  float*          buv  = (float*)(ws + 786432);            //     2,048 B
  float*          UVt  = (float*)(ws + 788480);            // 4,194,304 B
  float*          cvec = (float*)(ws + 4982784);           //    16,384 B

  prep_kernel<<<128, 256, 0, stream>>>(Wr, br, W1, b1, Wubf, buv, cvec);
  biggemm_kernel<<<dim3(64, 8), 256, 0, stream>>>(X, Wubf, buv, W2, UVt, cvec);
  pairwise_kernel<<<dim3(528, 2), 256, 0, stream>>>(UVt, W2, cvec, b2, Out);
}

// Round 11
// 55.689 us; speedup vs baseline: 1.3892x; 1.3892x over previous
//
#include <hip/hip_runtime.h>

typedef __attribute__((ext_vector_type(4))) float f32x4;
typedef __attribute__((ext_vector_type(8))) short bf16x8;

// f32 -> bf16 round-to-nearest-even
__device__ inline unsigned short f2bf(float x) {
  unsigned u = __builtin_bit_cast(unsigned, x);
  u += 0x7fffu + ((u >> 16) & 1u);
  return (unsigned short)(u >> 16);
}

__device__ inline bf16x8 pack8(f32x4 lo, f32x4 hi) {
  bf16x8 r;
  r[0] = (short)f2bf(lo[0]); r[1] = (short)f2bf(lo[1]);
  r[2] = (short)f2bf(lo[2]); r[3] = (short)f2bf(lo[3]);
  r[4] = (short)f2bf(hi[0]); r[5] = (short)f2bf(hi[1]);
  r[6] = (short)f2bf(hi[2]); r[7] = (short)f2bf(hi[3]);
  return r;
}

__device__ inline bf16x8 cvt8(const float* __restrict__ p) {
  return pack8(*(const f32x4*)p, *(const f32x4*)(p + 4));
}

// GEMM1: e[2048][128] = X @ Wr^T + br (bf16 out). One 16x16 tile per wave,
// inline f32->bf16 cvt of both operands (R1-proven). Also zeros cvec
// (blockIdx.y==0 slice) so gemm2's atomics land on clean memory.
__global__ __launch_bounds__(256) void gemm1_kernel(
    const float* __restrict__ X, const float* __restrict__ Wr,
    const float* __restrict__ br, unsigned short* __restrict__ Ebf,
    float* __restrict__ cvec) {
  if (blockIdx.y == 0) {
    int idx = blockIdx.x * 256 + threadIdx.x;  // 32*256 = 8192 >= 4096
    if (idx < 4096) cvec[idx] = 0.f;
  }
  int wave = threadIdx.x >> 6, lane = threadIdx.x & 63;
  int tok0 = (blockIdx.x * 4 + wave) * 16;
  int n0 = blockIdx.y * 16;
  int lr = lane & 15, kg = (lane >> 4) * 8;
  const float* ap = X + (size_t)(tok0 + lr) * 768 + kg;
  const float* bp = Wr + (size_t)(n0 + lr) * 768 + kg;
  f32x4 acc = {0, 0, 0, 0};
#pragma unroll 4
  for (int k0 = 0; k0 < 768; k0 += 32) {
    bf16x8 a = cvt8(ap + k0);
    bf16x8 b = cvt8(bp + k0);
    acc = __builtin_amdgcn_mfma_f32_16x16x32_bf16(a, b, acc, 0, 0, 0);
  }
  int rb = (lane >> 4) * 4;
  float bias = br[n0 + lr];
#pragma unroll
  for (int r = 0; r < 4; ++r)
    Ebf[(size_t)(tok0 + rb + r) * 128 + n0 + lr] = f2bf(acc[r] + bias);
}

// GEMM2 + fused cvec: UVt[512][2048] (0..255 = e@W1r^T + b1, 256..511 = e@W1c^T)
// W1 converted inline from f32 (R1-proven indexing); cvec via shfl-reduce +
// atomicAdd (R5-proven epilogue).
__global__ __launch_bounds__(256) void gemm2_kernel(
    const unsigned short* __restrict__ Ebf, const float* __restrict__ W1,
    const float* __restrict__ b1, const float* __restrict__ W2,
    float* __restrict__ UVt, float* __restrict__ cvec) {
  int wave = threadIdx.x >> 6, lane = threadIdx.x & 63;
  int t0 = blockIdx.x * 64;
  int m0 = (blockIdx.y * 4 + wave) * 16;
  int lr = lane & 15, kg = (lane >> 4) * 8;
  const float* aB = (m0 < 256)
      ? (W1 + (size_t)(m0 + lr) * 256 + kg)
      : (W1 + (size_t)(m0 - 256 + lr) * 256 + 128 + kg);
  f32x4 acc[4] = {{0,0,0,0},{0,0,0,0},{0,0,0,0},{0,0,0,0}};
#pragma unroll
  for (int k0 = 0; k0 < 128; k0 += 32) {
    bf16x8 a = cvt8(aB + k0);
#pragma unroll
    for (int t = 0; t < 4; ++t) {
      bf16x8 b = *(const bf16x8*)(Ebf + (size_t)(t0 + t * 16 + lr) * 128 + kg + k0);
      acc[t] = __builtin_amdgcn_mfma_f32_16x16x32_bf16(a, b, acc[t], 0, 0, 0);
    }
  }
  int rb = (lane >> 4) * 4;
  float p[4] = {0.f, 0.f, 0.f, 0.f};
#pragma unroll
  for (int t = 0; t < 4; ++t) {
#pragma unroll
    for (int r = 0; r < 4; ++r) {
      int m = m0 + rb + r;
      float val = acc[t][r] + ((m0 < 256) ? b1[m] : 0.f);
      UVt[(size_t)m * 2048 + t0 + t * 16 + lr] = val;
      p[t] = fmaf(W2[m & 255], val, p[t]);
    }
  }
#pragma unroll
  for (int t = 0; t < 4; ++t) {
    p[t] += __shfl_xor(p[t], 16);
    p[t] += __shfl_xor(p[t], 32);
  }
  if (lane < 16) {
    int h = (m0 < 256) ? 0 : 1;
#pragma unroll
    for (int t = 0; t < 4; ++t)
      atomicAdd(&cvec[h * 2048 + t0 + t * 16 + lane], 0.5f * p[t]);
  }
}

// Pairwise (R10-passed version, verbatim): 32x32 tile/block, 4 waves m-split,
// [m][tok] LDS, 4x4/lane abs-trick outer product; all-wave combine +
// mirrored writes via LDS.
__global__ __launch_bounds__(256, 2) void pairwise_kernel(
    const float* __restrict__ UVt, const float* __restrict__ W2,
    const float* __restrict__ cvec, const float* __restrict__ b2p,
    float* __restrict__ Out) {
  __shared__ float u_s[4][64][36];
  __shared__ float v_s[4][64][36];
  __shared__ float w2_s[256];
  __shared__ float cuv[64];

  int tid = threadIdx.x;
  int wave = tid >> 6, lane = tid & 63;
  int b = blockIdx.y;
  int p = blockIdx.x;
  int it = 0;
  while (p >= 32 - it) { p -= 32 - it; ++it; }
  int jt = it + p;

  int utok = b * 1024 + it * 32;
  int vtok = b * 1024 + jt * 32;

  w2_s[tid] = W2[tid];
  if (tid < 32) cuv[tid] = cvec[utok + tid];
  else if (tid < 64) cuv[tid] = cvec[2048 + vtok + (tid - 32)];
  __syncthreads();  // w2_s/cuv visible; main loop LDS is wave-private

  int mr = lane >> 3, tq = (lane & 7) * 4;
  int tx = lane & 7, ty = lane >> 3;
  float acc[4][4] = {{0,0,0,0},{0,0,0,0},{0,0,0,0},{0,0,0,0}};

  // stage this wave's 64-m slice
#pragma unroll
  for (int g = 0; g < 8; ++g) {
    int ml = g * 8 + mr;
    int m = wave * 64 + ml;
    *(f32x4*)&u_s[wave][ml][tq] = *(const f32x4*)(UVt + (size_t)m * 2048 + utok + tq);
    *(f32x4*)&v_s[wave][ml][tq] = *(const f32x4*)(UVt + (size_t)(256 + m) * 2048 + vtok + tq);
  }

  for (int ml = 0; ml < 64; ml += 4) {
    f32x4 wq = *(const f32x4*)&w2_s[wave * 64 + ml];
#pragma unroll
    for (int s = 0; s < 4; ++s) {
      f32x4 uu = *(const f32x4*)&u_s[wave][ml + s][4 * ty];
      f32x4 vv = *(const f32x4*)&v_s[wave][ml + s][4 * tx];
      float w = wq[s];
#pragma unroll
      for (int i = 0; i < 4; ++i)
#pragma unroll
        for (int j = 0; j < 4; ++j)
          acc[i][j] = fmaf(w, fabsf(uu[i] + vv[j]), acc[i][j]);
    }
  }

  // all-wave combine via LDS overlays
  float* ovp = (float*)u_s;   // [4][32][36] partials
  float* t2p = (float*)v_s;   // [32][36] transposed tile
  __syncthreads();            // all main-loop reads done before overlay writes
#pragma unroll
  for (int i = 0; i < 4; ++i) {
    f32x4 rv = {acc[i][0], acc[i][1], acc[i][2], acc[i][3]};
    *(f32x4*)&ovp[((size_t)wave * 32 + 4 * ty + i) * 36 + 4 * tx] = rv;
  }
  __syncthreads();

  int ly = lane >> 3, tc = lane & 7;   // row-within-wave, col group
  int row = wave * 8 + ly;
  float b2v = b2p[0];
  f32x4 sum = {0, 0, 0, 0};
#pragma unroll
  for (int q = 0; q < 4; ++q) {
    f32x4 part = *(const f32x4*)&ovp[((size_t)q * 32 + row) * 36 + 4 * tc];
#pragma unroll
    for (int j = 0; j < 4; ++j) sum[j] += part[j];
  }
  float cu = cuv[row];
  f32x4 val;
#pragma unroll
  for (int j = 0; j < 4; ++j)
    val[j] = 0.5f * sum[j] + cu + cuv[32 + 4 * tc + j] + b2v;

  // write transposed copy for mirror
  *(f32x4*)&t2p[(size_t)row * 36 + 4 * tc] = val;

  size_t obase = (size_t)b << 20;
  int i0 = it * 32, j0 = jt * 32;
  if (it != jt)
    *(f32x4*)(Out + obase + (size_t)(i0 + row) * 1024 + j0 + 4 * tc) = val;
  else {
#pragma unroll
    for (int j = 0; j < 4; ++j) {
      int jl = 4 * tc + j;
      if (jl >= row) Out[obase + (size_t)(i0 + row) * 1024 + j0 + jl] = val[j];
    }
  }
  __syncthreads();  // t2p complete
  f32x4 mv;
#pragma unroll
  for (int j = 0; j < 4; ++j) mv[j] = t2p[(size_t)(4 * tc + j) * 36 + row];
  if (it != jt)
    *(f32x4*)(Out + obase + (size_t)(j0 + row) * 1024 + i0 + 4 * tc) = mv;
  else {
#pragma unroll
    for (int j = 0; j < 4; ++j) {
      int c = 4 * tc + j;
      if (row > c) Out[obase + (size_t)(i0 + row) * 1024 + j0 + c] = mv[j];
    }
  }
}

extern "C" void kernel_launch(void* const* d_in, const int* in_sizes, int n_in,
                              void* d_out, int out_size, void* d_ws, size_t ws_size,
                              hipStream_t stream) {
  (void)in_sizes; (void)n_in; (void)out_size; (void)ws_size;
  const float* X  = (const float*)d_in[0];
  const float* Wr = (const float*)d_in[1];
  const float* br = (const float*)d_in[2];
  const float* W1 = (const float*)d_in[3];
  const float* b1 = (const float*)d_in[4];
  const float* W2 = (const float*)d_in[5];
  const float* b2 = (const float*)d_in[6];
  float* Out = (float*)d_out;

  char* ws = (char*)d_ws;
  unsigned short* Ebf  = (unsigned short*)(ws);            //   524,288 B
  float*          UVt  = (float*)(ws + 524288);            // 4,194,304 B
  float*          cvec = (float*)(ws + 4718592);           //    16,384 B

  gemm1_kernel<<<dim3(32, 8), 256, 0, stream>>>(X, Wr, br, Ebf, cvec);
  gemm2_kernel<<<dim3(32, 8), 256, 0, stream>>>(Ebf, W1, b1, W2, UVt, cvec);
  pairwise_kernel<<<dim3(528, 2), 256, 0, stream>>>(UVt, W2, cvec, b2, Out);
}